// Round 10
// baseline (945.973 us; speedup 1.0000x reference)
//
#include <hip/hip_runtime.h>

#define NL 16384          // row length
#define NB 64             // rows = blocks
#define NT 1024           // threads per block (16 waves = 4 waves/SIMD)
#define NC (NL / NT)      // 16 elements per thread
#define NW (NT / 64)      // 16 waves
#define N_ITER 12
#define N_IMFS 6

#pragma clang fp contract(off)   // everything unfused EXCEPT the explicit fmaf

#define HSZ (NL + (NL >> 5))   // +1 float per 32: 2-way-max banking (free)
__device__ __forceinline__ int physi(int i) { return i + (i >> 5); }

#define FMAXV 3.402823466e38f

// Frozen bit-exact semantics (R6 value path, absmax 0.0 across R6/R8/R9).
// R8 (lag-1) 277us, R9 (lag-2+ring) 325us: BOTH async protocols lost to
// R6's plain barrier (231us) => the per-iteration cost is the device-scope
// LLC round trip itself (acquire-poll == barrier), not the waiting. The only
// win is to not touch device memory every iteration.
// R20: batched decisions. Evidence: R6 runs exactly 78 decision points
// (6*12+6) -> conv NEVER fires early on this data -> running all 12 sift
// iterations unconditionally is free. Protocol:
//  - sift loop: 12 iters, t0 fire-and-forget posts (padded slots), 3 local
//    syncthreads/iter, ZERO device-scope reads/waits.
//  - per-IMF resolve: t0 scans slots 0..11 in order, first-true-wins
//    (exact JAX latch). Posted ~30us ago -> at most skew-bounded wait.
//  - recovery, no ring: j*==11 -> s_11 is in the other LDS dbuf (free);
//    j*<=10 -> REPLAY j* iterations from s_0 (= res, still untouched), posts
//    off. Replay only runs if early conv occurs (never on this data).
//  - flatness: full-IMF lag as R9 (resolve fcnt[k-1] at IMF k, instant).
__global__ __launch_bounds__(NT, 4) void emd_main(
    const float* __restrict__ x, float* __restrict__ out, char* __restrict__ ws) {
  // ---- workspace: 64B-strided control slots only ----
  unsigned* scnt = (unsigned*)ws;           // [72] sd arrival counters (x16 u32)
  double*   sdsl = (double*)(ws + 8192);    // [72] {m2,h2} (x8 dbl stride)
  unsigned* fcnt = (unsigned*)(ws + 16384); // [6] flat arrival counters (x16)
  double*   flsl = (double*)(ws + 20480);   // [6] {S1..S4} (x8 dbl stride)

  __shared__ float hbuf[2 * HSZ];   // 135168 B double-buffered h
  __shared__ int wLU[NW], wLL[NW], wNU[NW], wNL[NW];
  __shared__ float wMx[NW], wMn[NW];
  __shared__ unsigned wCT[NW];
  __shared__ int eLU[NW], eLL[NW], eNU[NW], eNL[NW];
  __shared__ float eMx[NW], eMn[NW];
  __shared__ unsigned sTot;
  __shared__ double tA[NW], tB[NW], tC[NW], tD[NW];
  __shared__ int sFlag, sJ;

  const int t = threadIdx.x;
  const int lane = t & 63;
  const int wv = t >> 6;
  const int row = blockIdx.x;
  const int base = t * NC;
  const float* xr = x + (size_t)row * NL;
  float* res = out + (size_t)N_IMFS * NB * NL + (size_t)row * NL;

  int off = 0;   // current h buffer offset (0 or HSZ), globally uniform

  // init: h = x row (LDS, swizzled); res slab of d_out = x
  #pragma unroll
  for (int q = 0; q < NC / 4; q++) {
    int i0 = base + q * 4;
    float4 v = *(const float4*)&xr[i0];
    *(float4*)&hbuf[physi(i0)] = v;
    *(float4*)&res[i0] = v;
  }
  __syncthreads();

  // one sift iteration: reads hcur, writes h_next into hnx.
  // post=true: block-reduce (pm2,ph2) and fire-and-forget post to slot.
  auto sift_iter = [&](float* hcur, float* hnx, int slot, bool post) {
    // pass A: chunked rolling walk -> peak masks + chunk summaries
    unsigned mU = 0, mL = 0;
    int lmU = -1, lmL = -1, cU = 0, cL = 0;
    float rmx = -FMAXV, rmn = FMAXV;
    {
      float hm = (base > 0) ? hcur[physi(base - 1)] : 0.0f;
      float4 cur = *(const float4*)&hcur[physi(base)];
      #define PKSTEP(J, HC, HP) { int i = base + (J);                     \
        bool in = (i > 0) && (i + 1 < NL);                                \
        if (in && hm < (HC) && (HC) > (HP)) { mU |= 1u << (J); lmU = i; cU++; } \
        if (in && hm > (HC) && (HC) < (HP)) { mL |= 1u << (J); lmL = i; cL++; } \
        rmx = fmaxf(rmx, (HC)); rmn = fminf(rmn, (HC)); hm = (HC); }
      #pragma unroll
      for (int q = 0; q < 4; q++) {
        float4 nxt = cur;
        float n0;
        if (q < 3) { nxt = *(const float4*)&hcur[physi(base + q * 4 + 4)]; n0 = nxt.x; }
        else       { n0 = (base + 16 < NL) ? hcur[physi(base + 16)] : 0.0f; }
        PKSTEP(q * 4 + 0, cur.x, cur.y)
        PKSTEP(q * 4 + 1, cur.y, cur.z)
        PKSTEP(q * 4 + 2, cur.z, cur.w)
        PKSTEP(q * 4 + 3, cur.w, n0)
        cur = nxt;
      }
      #undef PKSTEP
    }
    int fpU = mU ? (base + __ffs(mU) - 1) : NL;   // first own peak
    int fpL = mL ? (base + __ffs(mL) - 1) : NL;
    unsigned long long bUm = __ballot(mU != 0);
    unsigned long long bLm = __ballot(mL != 0);
    // wave summaries: owning lane stores directly (no scans)
    {
      int s;
      s = bUm ? (63 - __clzll((long long)bUm)) : 0;
      if (lane == s) wLU[wv] = bUm ? lmU : -1;
      s = bLm ? (63 - __clzll((long long)bLm)) : 0;
      if (lane == s) wLL[wv] = bLm ? lmL : -1;
      s = bUm ? (__ffsll(bUm) - 1) : 0;
      if (lane == s) wNU[wv] = bUm ? fpU : NL;
      s = bLm ? (__ffsll(bLm) - 1) : 0;
      if (lane == s) wNL[wv] = bLm ? fpL : NL;
    }
    // block peak-count totals (reduce only; same pairwise order as before)
    unsigned ict = ((unsigned)cU << 16) | (unsigned)cL;
    #pragma unroll
    for (int o = 1; o < 64; o <<= 1) {
      unsigned cc = __shfl_down(ict, o, 64);
      if (lane + o < 64) ict += cc;
    }
    if (lane == 0) wCT[wv] = ict;
    __syncthreads();   // S1
    if (t == 0) {      // 16-entry serial combine -> exclusive wave carries
      int aLU = -1, aLL = -1; unsigned tt = 0;
      for (int w = 0; w < NW; w++) {
        eLU[w] = aLU; aLU = max(aLU, wLU[w]);
        eLL[w] = aLL; aLL = max(aLL, wLL[w]);
        tt += wCT[w];
      }
      int aNU = NL, aNL = NL;
      for (int w = NW - 1; w >= 0; w--) {
        eNU[w] = aNU; aNU = min(aNU, wNU[w]);
        eNL[w] = aNL; aNL = min(aNL, wNL[w]);
      }
      sTot = tt;
    }
    __syncthreads();   // S2
    const unsigned tot = sTot;
    const int totU = (int)(tot >> 16), totL = (int)(tot & 0xffffu);

    // per-thread carries via ballot bit-ops + one dynamic shuffle each
    unsigned long long belowU = bUm & ((1ull << lane) - 1ull);
    unsigned long long belowL = bLm & ((1ull << lane) - 1ull);
    unsigned long long aboveU = (lane == 63) ? 0ull : (bUm & (~0ull << (lane + 1)));
    unsigned long long aboveL = (lane == 63) ? 0ull : (bLm & (~0ull << (lane + 1)));
    int slU = belowU ? (63 - __clzll((long long)belowU)) : 0;
    int slL = belowL ? (63 - __clzll((long long)belowL)) : 0;
    int snU = aboveU ? (__ffsll(aboveU) - 1) : 0;
    int snL = aboveL ? (__ffsll(aboveL) - 1) : 0;
    int gU  = __shfl(lmU, slU, 64);
    int gL  = __shfl(lmL, slL, 64);
    int gNU = __shfl(fpU, snU, 64);
    int gNL = __shfl(fpL, snL, 64);
    const int clU = belowU ? gU  : eLU[wv];
    const int clL = belowL ? gL  : eLL[wv];
    const int cnU = aboveU ? gNU : eNU[wv];
    const int cnL = aboveL ? gNL : eNL[wv];

    // Mx/Mn prefix carries only needed for the <2-peaks fallback (rare);
    // tot is block-uniform so the branch (and its barriers) is uniform.
    float crx = -FMAXV, crn = FMAXV;
    if (totU < 2 || totL < 2) {
      float iMx = rmx, iMn = rmn;
      #pragma unroll
      for (int o = 1; o < 64; o <<= 1) {
        float fa = __shfl_up(iMx, o, 64);
        float fb = __shfl_up(iMn, o, 64);
        if (lane >= o) { iMx = fmaxf(iMx, fa); iMn = fminf(iMn, fb); }
      }
      if (lane == 63) { wMx[wv] = iMx; wMn[wv] = iMn; }
      __syncthreads();
      if (t == 0) {
        float aMx = -FMAXV, aMn = FMAXV;
        for (int w = 0; w < NW; w++) {
          eMx[w] = aMx; aMx = fmaxf(aMx, wMx[w]);
          eMn[w] = aMn; aMn = fminf(aMn, wMn[w]);
        }
      }
      __syncthreads();
      float pMx = __shfl_up(iMx, 1, 64); if (lane == 0) pMx = -FMAXV;
      float pMn = __shfl_up(iMn, 1, 64); if (lane == 0) pMn = FMAXV;
      crx = fmaxf(eMx[wv], pMx);
      crn = fminf(eMn[wv], pMn);
    }

    // pass C: envelopes + mean (frozen f32 ladder), streaming b128 chunks;
    // h_next = hc - mn written inline to the other buffer (dbuf subtract).
    double pm2 = 0.0, ph2 = 0.0;
    {
      float rx = crx, rn = crn;
      int curLU = clU, curLL = clL;
      float vl = hcur[physi(clU < 0 ? 0 : clU)];   // carry-in gathers
      float wl = hcur[physi(clL < 0 ? 0 : clL)];
      int gB = -0x7fffffff, gD = -0x7fffffff;
      float vr = 0.0f, wr = 0.0f;
      #define ENVSTEP(J, HC, OD) { int i = base + (J); float hc = (HC);   \
        rx = fmaxf(rx, hc); rn = fminf(rn, hc);                           \
        if ((mU >> (J)) & 1u) { curLU = i; vl = hc; }                     \
        if ((mL >> (J)) & 1u) { curLL = i; wl = hc; }                     \
        int lU = curLU, lL = curLL;                                       \
        unsigned highm = 0xFFFFFFFFu << (J); unsigned a;                  \
        a = mU & highm; int nUv = a ? (base + __ffs(a) - 1) : cnU;        \
        a = mL & highm; int nLv = a ? (base + __ffs(a) - 1) : cnL;        \
        if (nUv != gB) { gB = nUv; vr = hcur[physi(nUv >= NL ? NL - 1 : nUv)]; } \
        if (nLv != gD) { gD = nLv; wr = hcur[physi(nLv >= NL ? NL - 1 : nLv)]; } \
        int den = nUv - lU;                                               \
        float fracU = (float)(i - lU) / (float)(den > 0 ? den : 1);       \
        float envU = (den > 0) ? __builtin_fmaf(fracU, vr - vl, vl) : vl; \
        if (lU < 0) envU = vr;                                            \
        if (nUv >= NL) envU = vl;                                         \
        if (totU < 2) envU = rx;                                          \
        int den2 = nLv - lL;                                              \
        float fracL = (float)(i - lL) / (float)(den2 > 0 ? den2 : 1);     \
        float envL = (den2 > 0) ? __builtin_fmaf(fracL, wr - wl, wl) : wl;\
        if (lL < 0) envL = wr;                                            \
        if (nLv >= NL) envL = wl;                                         \
        if (totL < 2) envL = rn;                                          \
        float mn = 0.5f * (envU + envL);                                  \
        (OD) = hc - mn;                                                   \
        pm2 += (double)mn * (double)mn; ph2 += (double)hc * (double)hc; }
      #pragma unroll
      for (int q = 0; q < 4; q++) {
        int i0 = base + q * 4;
        float4 hv4 = *(const float4*)&hcur[physi(i0)];
        float4 o4;
        ENVSTEP(q * 4 + 0, hv4.x, o4.x)
        ENVSTEP(q * 4 + 1, hv4.y, o4.y)
        ENVSTEP(q * 4 + 2, hv4.z, o4.z)
        ENVSTEP(q * 4 + 3, hv4.w, o4.w)
        *(float4*)&hnx[physi(i0)] = o4;
      }
      #undef ENVSTEP
    }
    if (post) {
      // fused block reduction of (pm2, ph2)
      #pragma unroll
      for (int o = 1; o < 64; o <<= 1) {
        double a = __shfl_down(pm2, o, 64);
        double b = __shfl_down(ph2, o, 64);
        if (lane + o < 64) { pm2 += a; ph2 += b; }
      }
      if (lane == 0) { tA[wv] = pm2; tB[wv] = ph2; }
      __syncthreads();   // S5: orders tA/tB + hnx writes (next pass A's dep)
      if (t == 0) {      // fire-and-forget post: NO device-scope reads/waits
        double sA = 0.0, sB = 0.0;
        for (int w = 0; w < NW; w++) { sA += tA[w]; sB += tB[w]; }
        atomicAdd(&sdsl[slot * 8 + 0], sA);
        atomicAdd(&sdsl[slot * 8 + 1], sB);
        __hip_atomic_fetch_add(&scnt[slot * 16], 1u, __ATOMIC_ACQ_REL, __HIP_MEMORY_SCOPE_AGENT);
      }
    } else {
      __syncthreads();   // order hnx writes before next pass A / reader
    }
  };

  bool done = false;

  for (int k = 0; k < N_IMFS; k++) {
    float* outk = out + (size_t)k * NB * NL + (size_t)row * NL;
    if (done) {  // resolved-done skip (uniform, no barriers, no posts)
      #pragma unroll
      for (int q = 0; q < NC / 4; q++)
        *(float4*)&outk[base + q * 4] = make_float4(0.f, 0.f, 0.f, 0.f);
      continue;
    }

    // ---- sifting: 12 iterations, zero device syncs ----
    for (int it = 0; it < N_ITER; it++) {
      sift_iter(hbuf + off, hbuf + (off ^ HSZ), k * N_ITER + it, true);
      off ^= HSZ;   // accept provisionally (dbuf holds s_{it} as well)
    }
    // ---- per-IMF resolve: first-true-wins over slots 0..11 ----
    if (t == 0) {
      int js = -1;
      for (int j = 0; j < N_ITER; j++) {
        int s = k * N_ITER + j;
        while (__hip_atomic_load(&scnt[s * 16], __ATOMIC_ACQUIRE, __HIP_MEMORY_SCOPE_AGENT) < NB)
          __builtin_amdgcn_s_sleep(1);
        double m2 = __hip_atomic_load(&sdsl[s * 8 + 0], __ATOMIC_RELAXED, __HIP_MEMORY_SCOPE_AGENT);
        double h2 = __hip_atomic_load(&sdsl[s * 8 + 1], __ATOMIC_RELAXED, __HIP_MEMORY_SCOPE_AGENT);
        if (m2 / (h2 + 1e-8) < 0.05) { js = j; break; }
      }
      sJ = js;
    }
    __syncthreads();
    {
      int js = sJ;
      if (js == N_ITER - 1) {
        off ^= HSZ;                 // s_11 still in the other dbuf half
      } else if (js >= 0) {
        // replay js iterations from s_0 (= res, untouched until outputs)
        float* hc = hbuf + off;
        #pragma unroll
        for (int q = 0; q < NC / 4; q++) {
          int i0 = base + q * 4;
          float4 v = *(const float4*)&res[i0];
          *(float4*)&hc[physi(i0)] = v;
        }
        __syncthreads();
        for (int r = 0; r < js; r++) {
          sift_iter(hbuf + off, hbuf + (off ^ HSZ), -1, false);
          off ^= HSZ;
        }
      }
    }

    float* hcur = hbuf + off;  // h_final

    // ---- resolve done_{k-1}: posted a full IMF ago -> instant ----
    if (k > 0) {
      if (t == 0) {
        while (__hip_atomic_load(&fcnt[(k - 1) * 16], __ATOMIC_ACQUIRE, __HIP_MEMORY_SCOPE_AGENT) < NB)
          __builtin_amdgcn_s_sleep(1);
        double S1 = __hip_atomic_load(&flsl[(k - 1) * 8 + 0], __ATOMIC_RELAXED, __HIP_MEMORY_SCOPE_AGENT);
        double S2 = __hip_atomic_load(&flsl[(k - 1) * 8 + 1], __ATOMIC_RELAXED, __HIP_MEMORY_SCOPE_AGENT);
        double S3 = __hip_atomic_load(&flsl[(k - 1) * 8 + 2], __ATOMIC_RELAXED, __HIP_MEMORY_SCOPE_AGENT);
        double S4 = __hip_atomic_load(&flsl[(k - 1) * 8 + 3], __ATOMIC_RELAXED, __HIP_MEMORY_SCOPE_AGENT);
        double nr = (double)NB * (double)NL;
        double nd = (double)NB * (double)(NL - 1);
        double varr = (S2 - S1 * S1 / nr) / (nr - 1.0);
        double vard = (S4 - S3 * S3 / nd) / (nd - 1.0);
        sFlag = (vard < 0.05 * varr) ? 1 : 0;
      }
      __syncthreads();
      if (sFlag) done = true;
    }
    if (done) {  // flat at k-1: this IMF's sifting is discarded (ref: zeros)
      #pragma unroll
      for (int q = 0; q < NC / 4; q++)
        *(float4*)&outk[base + q * 4] = make_float4(0.f, 0.f, 0.f, 0.f);
      continue;
    }

    // ------------- flatness partials (f32 values, f64 sums) -------------
    double s1 = 0.0, s2 = 0.0, s3 = 0.0, s4 = 0.0;
    {
      float rb = 0.0f;   // res-h at base+NC (next thread's first element)
      if (base + NC < NL) rb = res[base + NC] - hcur[physi(base + NC)];
      float4 rv4 = *(const float4*)&res[base];
      float4 hv4 = *(const float4*)&hcur[physi(base)];
      float e0 = rv4.x - hv4.x, e1 = rv4.y - hv4.y,
            e2 = rv4.z - hv4.z, e3 = rv4.w - hv4.w;
      #define FLSTEP(J, CUR, NXT) { int i = base + (J);                     \
        s1 += (double)(CUR); s2 += (double)(CUR) * (double)(CUR);           \
        if (i + 1 < NL) { float dd = (NXT) - (CUR);                         \
          s3 += (double)dd; s4 += (double)dd * (double)dd; } }
      #pragma unroll
      for (int q = 0; q < 4; q++) {
        float c0 = e0, c1 = e1, c2 = e2, c3 = e3;
        float n0;
        if (q < 3) {
          int i0 = base + q * 4 + 4;
          rv4 = *(const float4*)&res[i0];
          hv4 = *(const float4*)&hcur[physi(i0)];
          e0 = rv4.x - hv4.x; e1 = rv4.y - hv4.y;
          e2 = rv4.z - hv4.z; e3 = rv4.w - hv4.w;
          n0 = e0;
        } else n0 = rb;
        FLSTEP(q * 4 + 0, c0, c1)
        FLSTEP(q * 4 + 1, c1, c2)
        FLSTEP(q * 4 + 2, c2, c3)
        FLSTEP(q * 4 + 3, c3, n0)
      }
      #undef FLSTEP
    }
    #pragma unroll
    for (int o = 1; o < 64; o <<= 1) {
      double a = __shfl_down(s1, o, 64);
      double b = __shfl_down(s2, o, 64);
      double c = __shfl_down(s3, o, 64);
      double d = __shfl_down(s4, o, 64);
      if (lane + o < 64) { s1 += a; s2 += b; s3 += c; s4 += d; }
    }
    if (lane == 0) { tA[wv] = s1; tB[wv] = s2; tC[wv] = s3; tD[wv] = s4; }
    __syncthreads();   // orders publishes AND all cross-thread h/res reads above
    if (t == 0) {      // post flat partials + arrival -- NO WAIT (full-IMF lag)
      double S1 = 0.0, S2 = 0.0, S3 = 0.0, S4 = 0.0;
      for (int w = 0; w < NW; w++) { S1 += tA[w]; S2 += tB[w]; S3 += tC[w]; S4 += tD[w]; }
      atomicAdd(&flsl[k * 8 + 0], S1);
      atomicAdd(&flsl[k * 8 + 1], S2);
      atomicAdd(&flsl[k * 8 + 2], S3);
      atomicAdd(&flsl[k * 8 + 3], S4);
      __hip_atomic_fetch_add(&fcnt[k * 16], 1u, __ATOMIC_ACQ_REL, __HIP_MEMORY_SCOPE_AGENT);
    }
    // outputs: IMF k = h; res -= h; h <- new res (current buffer)
    #pragma unroll
    for (int q = 0; q < NC / 4; q++) {
      int i0 = base + q * 4;
      int p0 = physi(i0);
      float4 rv = *(const float4*)&res[i0];
      float4 hv = *(const float4*)&hcur[p0];
      float4 rq = make_float4(rv.x - hv.x, rv.y - hv.y, rv.z - hv.z, rv.w - hv.w);
      *(float4*)&outk[i0] = hv;
      *(float4*)&res[i0] = rq;
      *(float4*)&hcur[p0] = rq;
    }
    __syncthreads();   // orders h <- res writes before next IMF's pass A
  }
}

extern "C" void kernel_launch(void* const* d_in, const int* in_sizes, int n_in,
                              void* d_out, int out_size, void* d_ws, size_t ws_size,
                              hipStream_t stream) {
  const float* x = (const float*)d_in[0];
  float* out = (float*)d_out;
  // ws: [0] scnt 72x64B; [8192] sdsl 72x64B; [16384] fcnt 6x64B; [20480] flsl 6x64B
  size_t zb = ws_size < 32768 ? ws_size : 32768;
  hipMemsetAsync(d_ws, 0, zb, stream);
  hipLaunchKernelGGL(emd_main, dim3(NB), dim3(NT), 0, stream,
                     x, out, (char*)d_ws);
}

// Round 11
// 321.036 us; speedup vs baseline: 2.9466x; 2.9466x over previous
//
#include <hip/hip_runtime.h>

#define NL 16384          // row length
#define NB 64             // rows = blocks
#define NT 1024           // threads per block (16 waves = 4 waves/SIMD)
#define NC (NL / NT)      // 16 elements per thread
#define NW (NT / 64)      // 16 waves
#define N_ITER 12
#define N_IMFS 6

#pragma clang fp contract(off)   // everything unfused EXCEPT the explicit fmaf

#define HSZ (NL + (NL >> 5))   // +1 float per 32: 2-way-max banking (free)
__device__ __forceinline__ int physi(int i) { return i + (i >> 5); }

#define FMAXV 3.402823466e38f

// Frozen bit-exact semantics (R6 value path, absmax 0.0 across R6/R8/R9/R10).
// R10's bank-conflict counter (2.01M vs R6's 0.33M = 6.1x) revealed the key
// fact: conv fires at j* ~= 1-2 per IMF (R6 executes ~14-20 sift iters
// total, not 72). R10 (batch-all-12) did 4x the work -> 897us. R8/R9 async
// kept a device round trip per iter -> lost. R6's 231us ~= 100-130us of
// ~20 barrier epochs + local work.
// R21: exploit early conv the cheap way -- pair-resolve iters {0,1}:
//  - run iter 0 and iter 1 with fire-and-forget posts, then ONE wait
//    resolves conv_0 (first-true-wins) then conv_1.
//  - recovery exact, zero state: j*=0 -> s_0 = res (copy back);
//    j*=1 -> s_1 in the other dbuf half (flip back).
//  - j*>=2 (rare): per-iteration R6 mode (iter j, resolve conv_j, s_j in
//    other buffer).
//  - flat decision: full-IMF lag (R10 mechanism, proven) -> no flat wait.
// Waits/IMF: R6 ~3.3 -> max(1, j*) ~1.3. Value ladder byte-identical.
__global__ __launch_bounds__(NT, 4) void emd_main(
    const float* __restrict__ x, float* __restrict__ out, char* __restrict__ ws) {
  // ---- workspace: 64B-strided control slots only ----
  unsigned* scnt = (unsigned*)ws;           // [72] sd arrival counters (x16 u32)
  double*   sdsl = (double*)(ws + 8192);    // [72] {m2,h2} (x8 dbl stride)
  unsigned* fcnt = (unsigned*)(ws + 16384); // [6] flat arrival counters (x16)
  double*   flsl = (double*)(ws + 20480);   // [6] {S1..S4} (x8 dbl stride)

  __shared__ float hbuf[2 * HSZ];   // 135168 B double-buffered h
  __shared__ int wLU[NW], wLL[NW], wNU[NW], wNL[NW];
  __shared__ float wMx[NW], wMn[NW];
  __shared__ unsigned wCT[NW];
  __shared__ int eLU[NW], eLL[NW], eNU[NW], eNL[NW];
  __shared__ float eMx[NW], eMn[NW];
  __shared__ unsigned sTot;
  __shared__ double tA[NW], tB[NW], tC[NW], tD[NW];
  __shared__ int sFlag, sJ;

  const int t = threadIdx.x;
  const int lane = t & 63;
  const int wv = t >> 6;
  const int row = blockIdx.x;
  const int base = t * NC;
  const float* xr = x + (size_t)row * NL;
  float* res = out + (size_t)N_IMFS * NB * NL + (size_t)row * NL;

  int off = 0;   // current h buffer offset (0 or HSZ), globally uniform

  // init: h = x row (LDS, swizzled); res slab of d_out = x
  #pragma unroll
  for (int q = 0; q < NC / 4; q++) {
    int i0 = base + q * 4;
    float4 v = *(const float4*)&xr[i0];
    *(float4*)&hbuf[physi(i0)] = v;
    *(float4*)&res[i0] = v;
  }
  __syncthreads();

  // one sift iteration: reads hcur, writes h_next into hnx; fire-and-forget
  // posts (pm2,ph2) to slot. No device-scope reads/waits.
  auto sift_iter = [&](float* hcur, float* hnx, int slot) {
    // pass A: chunked rolling walk -> peak masks + chunk summaries
    unsigned mU = 0, mL = 0;
    int lmU = -1, lmL = -1, cU = 0, cL = 0;
    float rmx = -FMAXV, rmn = FMAXV;
    {
      float hm = (base > 0) ? hcur[physi(base - 1)] : 0.0f;
      float4 cur = *(const float4*)&hcur[physi(base)];
      #define PKSTEP(J, HC, HP) { int i = base + (J);                     \
        bool in = (i > 0) && (i + 1 < NL);                                \
        if (in && hm < (HC) && (HC) > (HP)) { mU |= 1u << (J); lmU = i; cU++; } \
        if (in && hm > (HC) && (HC) < (HP)) { mL |= 1u << (J); lmL = i; cL++; } \
        rmx = fmaxf(rmx, (HC)); rmn = fminf(rmn, (HC)); hm = (HC); }
      #pragma unroll
      for (int q = 0; q < 4; q++) {
        float4 nxt = cur;
        float n0;
        if (q < 3) { nxt = *(const float4*)&hcur[physi(base + q * 4 + 4)]; n0 = nxt.x; }
        else       { n0 = (base + 16 < NL) ? hcur[physi(base + 16)] : 0.0f; }
        PKSTEP(q * 4 + 0, cur.x, cur.y)
        PKSTEP(q * 4 + 1, cur.y, cur.z)
        PKSTEP(q * 4 + 2, cur.z, cur.w)
        PKSTEP(q * 4 + 3, cur.w, n0)
        cur = nxt;
      }
      #undef PKSTEP
    }
    int fpU = mU ? (base + __ffs(mU) - 1) : NL;   // first own peak
    int fpL = mL ? (base + __ffs(mL) - 1) : NL;
    unsigned long long bUm = __ballot(mU != 0);
    unsigned long long bLm = __ballot(mL != 0);
    // wave summaries: owning lane stores directly (no scans)
    {
      int s;
      s = bUm ? (63 - __clzll((long long)bUm)) : 0;
      if (lane == s) wLU[wv] = bUm ? lmU : -1;
      s = bLm ? (63 - __clzll((long long)bLm)) : 0;
      if (lane == s) wLL[wv] = bLm ? lmL : -1;
      s = bUm ? (__ffsll(bUm) - 1) : 0;
      if (lane == s) wNU[wv] = bUm ? fpU : NL;
      s = bLm ? (__ffsll(bLm) - 1) : 0;
      if (lane == s) wNL[wv] = bLm ? fpL : NL;
    }
    // block peak-count totals (reduce only; same pairwise order as before)
    unsigned ict = ((unsigned)cU << 16) | (unsigned)cL;
    #pragma unroll
    for (int o = 1; o < 64; o <<= 1) {
      unsigned cc = __shfl_down(ict, o, 64);
      if (lane + o < 64) ict += cc;
    }
    if (lane == 0) wCT[wv] = ict;
    __syncthreads();   // S1
    if (t == 0) {      // 16-entry serial combine -> exclusive wave carries
      int aLU = -1, aLL = -1; unsigned tt = 0;
      for (int w = 0; w < NW; w++) {
        eLU[w] = aLU; aLU = max(aLU, wLU[w]);
        eLL[w] = aLL; aLL = max(aLL, wLL[w]);
        tt += wCT[w];
      }
      int aNU = NL, aNL = NL;
      for (int w = NW - 1; w >= 0; w--) {
        eNU[w] = aNU; aNU = min(aNU, wNU[w]);
        eNL[w] = aNL; aNL = min(aNL, wNL[w]);
      }
      sTot = tt;
    }
    __syncthreads();   // S2
    const unsigned tot = sTot;
    const int totU = (int)(tot >> 16), totL = (int)(tot & 0xffffu);

    // per-thread carries via ballot bit-ops + one dynamic shuffle each
    unsigned long long belowU = bUm & ((1ull << lane) - 1ull);
    unsigned long long belowL = bLm & ((1ull << lane) - 1ull);
    unsigned long long aboveU = (lane == 63) ? 0ull : (bUm & (~0ull << (lane + 1)));
    unsigned long long aboveL = (lane == 63) ? 0ull : (bLm & (~0ull << (lane + 1)));
    int slU = belowU ? (63 - __clzll((long long)belowU)) : 0;
    int slL = belowL ? (63 - __clzll((long long)belowL)) : 0;
    int snU = aboveU ? (__ffsll(aboveU) - 1) : 0;
    int snL = aboveL ? (__ffsll(aboveL) - 1) : 0;
    int gU  = __shfl(lmU, slU, 64);
    int gL  = __shfl(lmL, slL, 64);
    int gNU = __shfl(fpU, snU, 64);
    int gNL = __shfl(fpL, snL, 64);
    const int clU = belowU ? gU  : eLU[wv];
    const int clL = belowL ? gL  : eLL[wv];
    const int cnU = aboveU ? gNU : eNU[wv];
    const int cnL = aboveL ? gNL : eNL[wv];

    // Mx/Mn prefix carries only needed for the <2-peaks fallback (rare);
    // tot is block-uniform so the branch (and its barriers) is uniform.
    float crx = -FMAXV, crn = FMAXV;
    if (totU < 2 || totL < 2) {
      float iMx = rmx, iMn = rmn;
      #pragma unroll
      for (int o = 1; o < 64; o <<= 1) {
        float fa = __shfl_up(iMx, o, 64);
        float fb = __shfl_up(iMn, o, 64);
        if (lane >= o) { iMx = fmaxf(iMx, fa); iMn = fminf(iMn, fb); }
      }
      if (lane == 63) { wMx[wv] = iMx; wMn[wv] = iMn; }
      __syncthreads();
      if (t == 0) {
        float aMx = -FMAXV, aMn = FMAXV;
        for (int w = 0; w < NW; w++) {
          eMx[w] = aMx; aMx = fmaxf(aMx, wMx[w]);
          eMn[w] = aMn; aMn = fminf(aMn, wMn[w]);
        }
      }
      __syncthreads();
      float pMx = __shfl_up(iMx, 1, 64); if (lane == 0) pMx = -FMAXV;
      float pMn = __shfl_up(iMn, 1, 64); if (lane == 0) pMn = FMAXV;
      crx = fmaxf(eMx[wv], pMx);
      crn = fminf(eMn[wv], pMn);
    }

    // pass C: envelopes + mean (frozen f32 ladder), streaming b128 chunks;
    // h_next = hc - mn written inline to the other buffer (dbuf subtract).
    double pm2 = 0.0, ph2 = 0.0;
    {
      float rx = crx, rn = crn;
      int curLU = clU, curLL = clL;
      float vl = hcur[physi(clU < 0 ? 0 : clU)];   // carry-in gathers
      float wl = hcur[physi(clL < 0 ? 0 : clL)];
      int gB = -0x7fffffff, gD = -0x7fffffff;
      float vr = 0.0f, wr = 0.0f;
      #define ENVSTEP(J, HC, OD) { int i = base + (J); float hc = (HC);   \
        rx = fmaxf(rx, hc); rn = fminf(rn, hc);                           \
        if ((mU >> (J)) & 1u) { curLU = i; vl = hc; }                     \
        if ((mL >> (J)) & 1u) { curLL = i; wl = hc; }                     \
        int lU = curLU, lL = curLL;                                       \
        unsigned highm = 0xFFFFFFFFu << (J); unsigned a;                  \
        a = mU & highm; int nUv = a ? (base + __ffs(a) - 1) : cnU;        \
        a = mL & highm; int nLv = a ? (base + __ffs(a) - 1) : cnL;        \
        if (nUv != gB) { gB = nUv; vr = hcur[physi(nUv >= NL ? NL - 1 : nUv)]; } \
        if (nLv != gD) { gD = nLv; wr = hcur[physi(nLv >= NL ? NL - 1 : nLv)]; } \
        int den = nUv - lU;                                               \
        float fracU = (float)(i - lU) / (float)(den > 0 ? den : 1);       \
        float envU = (den > 0) ? __builtin_fmaf(fracU, vr - vl, vl) : vl; \
        if (lU < 0) envU = vr;                                            \
        if (nUv >= NL) envU = vl;                                         \
        if (totU < 2) envU = rx;                                          \
        int den2 = nLv - lL;                                              \
        float fracL = (float)(i - lL) / (float)(den2 > 0 ? den2 : 1);     \
        float envL = (den2 > 0) ? __builtin_fmaf(fracL, wr - wl, wl) : wl;\
        if (lL < 0) envL = wr;                                            \
        if (nLv >= NL) envL = wl;                                         \
        if (totL < 2) envL = rn;                                          \
        float mn = 0.5f * (envU + envL);                                  \
        (OD) = hc - mn;                                                   \
        pm2 += (double)mn * (double)mn; ph2 += (double)hc * (double)hc; }
      #pragma unroll
      for (int q = 0; q < 4; q++) {
        int i0 = base + q * 4;
        float4 hv4 = *(const float4*)&hcur[physi(i0)];
        float4 o4;
        ENVSTEP(q * 4 + 0, hv4.x, o4.x)
        ENVSTEP(q * 4 + 1, hv4.y, o4.y)
        ENVSTEP(q * 4 + 2, hv4.z, o4.z)
        ENVSTEP(q * 4 + 3, hv4.w, o4.w)
        *(float4*)&hnx[physi(i0)] = o4;
      }
      #undef ENVSTEP
    }
    // fused block reduction of (pm2, ph2)
    #pragma unroll
    for (int o = 1; o < 64; o <<= 1) {
      double a = __shfl_down(pm2, o, 64);
      double b = __shfl_down(ph2, o, 64);
      if (lane + o < 64) { pm2 += a; ph2 += b; }
    }
    if (lane == 0) { tA[wv] = pm2; tB[wv] = ph2; }
    __syncthreads();   // S5: orders tA/tB + hnx writes (next pass A's dep)
    if (t == 0) {      // fire-and-forget post: NO device-scope reads/waits
      double sA = 0.0, sB = 0.0;
      for (int w = 0; w < NW; w++) { sA += tA[w]; sB += tB[w]; }
      atomicAdd(&sdsl[slot * 8 + 0], sA);
      atomicAdd(&sdsl[slot * 8 + 1], sB);
      __hip_atomic_fetch_add(&scnt[slot * 16], 1u, __ATOMIC_ACQ_REL, __HIP_MEMORY_SCOPE_AGENT);
    }
  };

  // t0 helper: wait for slot completion, return conv flag
  auto resolve = [&](int slot) -> int {
    while (__hip_atomic_load(&scnt[slot * 16], __ATOMIC_ACQUIRE, __HIP_MEMORY_SCOPE_AGENT) < NB)
      __builtin_amdgcn_s_sleep(1);
    double m2 = __hip_atomic_load(&sdsl[slot * 8 + 0], __ATOMIC_RELAXED, __HIP_MEMORY_SCOPE_AGENT);
    double h2 = __hip_atomic_load(&sdsl[slot * 8 + 1], __ATOMIC_RELAXED, __HIP_MEMORY_SCOPE_AGENT);
    return (m2 / (h2 + 1e-8) < 0.05) ? 1 : 0;
  };

  bool done = false;

  for (int k = 0; k < N_IMFS; k++) {
    float* outk = out + (size_t)k * NB * NL + (size_t)row * NL;
    if (done) {  // resolved-done skip (uniform, no barriers, no posts)
      #pragma unroll
      for (int q = 0; q < NC / 4; q++)
        *(float4*)&outk[base + q * 4] = make_float4(0.f, 0.f, 0.f, 0.f);
      continue;
    }

    // ---- sifting: pair {0,1} fire-and-forget, then one resolve ----
    sift_iter(hbuf + off, hbuf + (off ^ HSZ), k * N_ITER + 0);
    off ^= HSZ;
    sift_iter(hbuf + off, hbuf + (off ^ HSZ), k * N_ITER + 1);
    off ^= HSZ;
    if (t == 0) {
      int js = -1;
      if (resolve(k * N_ITER + 0)) js = 0;
      else if (resolve(k * N_ITER + 1)) js = 1;
      sJ = js;
    }
    __syncthreads();
    {
      int js = sJ;
      if (js == 0) {          // h frozen at s_0 = res: copy back into cur
        float* hc = hbuf + off;
        #pragma unroll
        for (int q = 0; q < NC / 4; q++) {
          int i0 = base + q * 4;
          float4 v = *(const float4*)&res[i0];
          *(float4*)&hc[physi(i0)] = v;
        }
        __syncthreads();
      } else if (js == 1) {   // h frozen at s_1: other dbuf half
        off ^= HSZ;
      } else {                // j* >= 2 or none: per-iteration R6 mode
        for (int j = 2; j < N_ITER; j++) {
          sift_iter(hbuf + off, hbuf + (off ^ HSZ), k * N_ITER + j);
          off ^= HSZ;
          if (t == 0) sFlag = resolve(k * N_ITER + j);
          __syncthreads();
          if (sFlag) { off ^= HSZ; break; }   // h frozen at s_j
        }
      }
    }

    float* hcur = hbuf + off;  // h_final

    // ---- resolve done_{k-1}: posted a full IMF ago -> instant ----
    if (k > 0) {
      if (t == 0) {
        while (__hip_atomic_load(&fcnt[(k - 1) * 16], __ATOMIC_ACQUIRE, __HIP_MEMORY_SCOPE_AGENT) < NB)
          __builtin_amdgcn_s_sleep(1);
        double S1 = __hip_atomic_load(&flsl[(k - 1) * 8 + 0], __ATOMIC_RELAXED, __HIP_MEMORY_SCOPE_AGENT);
        double S2 = __hip_atomic_load(&flsl[(k - 1) * 8 + 1], __ATOMIC_RELAXED, __HIP_MEMORY_SCOPE_AGENT);
        double S3 = __hip_atomic_load(&flsl[(k - 1) * 8 + 2], __ATOMIC_RELAXED, __HIP_MEMORY_SCOPE_AGENT);
        double S4 = __hip_atomic_load(&flsl[(k - 1) * 8 + 3], __ATOMIC_RELAXED, __HIP_MEMORY_SCOPE_AGENT);
        double nr = (double)NB * (double)NL;
        double nd = (double)NB * (double)(NL - 1);
        double varr = (S2 - S1 * S1 / nr) / (nr - 1.0);
        double vard = (S4 - S3 * S3 / nd) / (nd - 1.0);
        sFlag = (vard < 0.05 * varr) ? 1 : 0;
      }
      __syncthreads();
      if (sFlag) done = true;
    }
    if (done) {  // flat at k-1: this IMF's sifting is discarded (ref: zeros)
      #pragma unroll
      for (int q = 0; q < NC / 4; q++)
        *(float4*)&outk[base + q * 4] = make_float4(0.f, 0.f, 0.f, 0.f);
      continue;
    }

    // ------------- flatness partials (f32 values, f64 sums) -------------
    double s1 = 0.0, s2 = 0.0, s3 = 0.0, s4 = 0.0;
    {
      float rb = 0.0f;   // res-h at base+NC (next thread's first element)
      if (base + NC < NL) rb = res[base + NC] - hcur[physi(base + NC)];
      float4 rv4 = *(const float4*)&res[base];
      float4 hv4 = *(const float4*)&hcur[physi(base)];
      float e0 = rv4.x - hv4.x, e1 = rv4.y - hv4.y,
            e2 = rv4.z - hv4.z, e3 = rv4.w - hv4.w;
      #define FLSTEP(J, CUR, NXT) { int i = base + (J);                     \
        s1 += (double)(CUR); s2 += (double)(CUR) * (double)(CUR);           \
        if (i + 1 < NL) { float dd = (NXT) - (CUR);                         \
          s3 += (double)dd; s4 += (double)dd * (double)dd; } }
      #pragma unroll
      for (int q = 0; q < 4; q++) {
        float c0 = e0, c1 = e1, c2 = e2, c3 = e3;
        float n0;
        if (q < 3) {
          int i0 = base + q * 4 + 4;
          rv4 = *(const float4*)&res[i0];
          hv4 = *(const float4*)&hcur[physi(i0)];
          e0 = rv4.x - hv4.x; e1 = rv4.y - hv4.y;
          e2 = rv4.z - hv4.z; e3 = rv4.w - hv4.w;
          n0 = e0;
        } else n0 = rb;
        FLSTEP(q * 4 + 0, c0, c1)
        FLSTEP(q * 4 + 1, c1, c2)
        FLSTEP(q * 4 + 2, c2, c3)
        FLSTEP(q * 4 + 3, c3, n0)
      }
      #undef FLSTEP
    }
    #pragma unroll
    for (int o = 1; o < 64; o <<= 1) {
      double a = __shfl_down(s1, o, 64);
      double b = __shfl_down(s2, o, 64);
      double c = __shfl_down(s3, o, 64);
      double d = __shfl_down(s4, o, 64);
      if (lane + o < 64) { s1 += a; s2 += b; s3 += c; s4 += d; }
    }
    if (lane == 0) { tA[wv] = s1; tB[wv] = s2; tC[wv] = s3; tD[wv] = s4; }
    __syncthreads();   // orders publishes AND all cross-thread h/res reads above
    if (t == 0) {      // post flat partials + arrival -- NO WAIT (full-IMF lag)
      double S1 = 0.0, S2 = 0.0, S3 = 0.0, S4 = 0.0;
      for (int w = 0; w < NW; w++) { S1 += tA[w]; S2 += tB[w]; S3 += tC[w]; S4 += tD[w]; }
      atomicAdd(&flsl[k * 8 + 0], S1);
      atomicAdd(&flsl[k * 8 + 1], S2);
      atomicAdd(&flsl[k * 8 + 2], S3);
      atomicAdd(&flsl[k * 8 + 3], S4);
      __hip_atomic_fetch_add(&fcnt[k * 16], 1u, __ATOMIC_ACQ_REL, __HIP_MEMORY_SCOPE_AGENT);
    }
    // outputs: IMF k = h; res -= h; h <- new res (current buffer)
    #pragma unroll
    for (int q = 0; q < NC / 4; q++) {
      int i0 = base + q * 4;
      int p0 = physi(i0);
      float4 rv = *(const float4*)&res[i0];
      float4 hv = *(const float4*)&hcur[p0];
      float4 rq = make_float4(rv.x - hv.x, rv.y - hv.y, rv.z - hv.z, rv.w - hv.w);
      *(float4*)&outk[i0] = hv;
      *(float4*)&res[i0] = rq;
      *(float4*)&hcur[p0] = rq;
    }
    __syncthreads();   // orders h <- res writes before next IMF's pass A
  }
}

extern "C" void kernel_launch(void* const* d_in, const int* in_sizes, int n_in,
                              void* d_out, int out_size, void* d_ws, size_t ws_size,
                              hipStream_t stream) {
  const float* x = (const float*)d_in[0];
  float* out = (float*)d_out;
  // ws: [0] scnt 72x64B; [8192] sdsl 72x64B; [16384] fcnt 6x64B; [20480] flsl 6x64B
  size_t zb = ws_size < 32768 ? ws_size : 32768;
  hipMemsetAsync(d_ws, 0, zb, stream);
  hipLaunchKernelGGL(emd_main, dim3(NB), dim3(NT), 0, stream,
                     x, out, (char*)d_ws);
}

// Round 12
// 283.749 us; speedup vs baseline: 3.3338x; 1.1314x over previous
//
#include <hip/hip_runtime.h>

#define NL 16384          // row length
#define NB 64             // rows = blocks
#define NT 1024           // threads per block (16 waves = 4 waves/SIMD)
#define NC (NL / NT)      // 16 elements per thread
#define NW (NT / 64)      // 16 waves
#define N_ITER 12
#define N_IMFS 6

#pragma clang fp contract(off)   // everything unfused EXCEPT the explicit fmaf

#define HSZ (NL + (NL >> 5))   // +1 float per 32: 2-way-max banking (free)
__device__ __forceinline__ int physi(int i) { return i + (i >> 5); }

#define FMAXV 3.402823466e38f

// Frozen bit-exact semantics (R6 value path, absmax 0.0 across R6/R8-R11).
// Protocol verdict after 5 experiments (R7 +157us, R8 +46, R9 +93, R10 +666,
// R11 +37): R6's plain centralized ticket barrier (1 grid decision per sift
// iter, inline flat decision) is empirically optimal -- every async/lagged/
// batched variant lost. Protocol frozen as R6.
// R22 (this): local-work diet on pass A, value-identical:
//  - pass A loop builds ONLY the peak masks mU/mL (2 cmp + bit-set per elem);
//    lmU/lmL = base+31-clz(mask), fpU/fpL = base+ffs-1, cU/cL = popc(mask)
//    derived after the loop (identical values, ~60 fewer inst/iter).
//  - rmx/rmn (chunk max/min) consumed ONLY in the rare <2-peaks fallback ->
//    recomputed there from hcur (untouched since pass A) in the same rolling
//    order. ~32 fewer inst/iter on the hot path.
// Pass C, reductions, decisions, outputs: byte-identical to R6.
__global__ __launch_bounds__(NT, 4) void emd_main(
    const float* __restrict__ x, float* __restrict__ out,
    unsigned* cnt, double* sdsl, double* flsl) {
  __shared__ float hbuf[2 * HSZ];   // 135168 B: double-buffered h
  __shared__ int wLU[NW], wLL[NW], wNU[NW], wNL[NW];
  __shared__ float wMx[NW], wMn[NW];
  __shared__ unsigned wCT[NW];
  __shared__ int eLU[NW], eLL[NW], eNU[NW], eNL[NW];
  __shared__ float eMx[NW], eMn[NW];
  __shared__ unsigned sTot;
  __shared__ double tA[NW], tB[NW], tC[NW], tD[NW];
  __shared__ int sFlag;

  const int t = threadIdx.x;
  const int lane = t & 63;
  const int wv = t >> 6;
  const int row = blockIdx.x;
  const int base = t * NC;
  const float* xr = x + (size_t)row * NL;
  float* res = out + (size_t)N_IMFS * NB * NL + (size_t)row * NL;

  int off = 0;   // current h buffer offset (0 or HSZ), block-uniform

  // init: h = x row (LDS, swizzled); res slab of d_out = x
  #pragma unroll
  for (int q = 0; q < NC / 4; q++) {
    int i0 = base + q * 4;
    float4 v = *(const float4*)&xr[i0];
    *(float4*)&hbuf[physi(i0)] = v;
    *(float4*)&res[i0] = v;
  }
  __syncthreads();

  unsigned ep = 0;
  bool done = false;

  for (int k = 0; k < N_IMFS; k++) {
    float* outk = out + (size_t)k * NB * NL + (size_t)row * NL;
    if (done) {  // globally-uniform skip (no barriers)
      #pragma unroll
      for (int q = 0; q < NC / 4; q++)
        *(float4*)&outk[base + q * 4] = make_float4(0.f, 0.f, 0.f, 0.f);
      continue;
    }

    // ---------------- sifting ----------------
    for (int it = 0; it < N_ITER; it++) {
      float* hcur = hbuf + off;
      float* hnx  = hbuf + (off ^ HSZ);

      // pass A: chunked rolling walk -> peak masks ONLY (R22 diet)
      unsigned mU = 0, mL = 0;
      {
        float hm = (base > 0) ? hcur[physi(base - 1)] : 0.0f;
        float4 cur = *(const float4*)&hcur[physi(base)];
        #define PKSTEP(J, HC, HP) { int i = base + (J);                     \
          bool in = (i > 0) && (i + 1 < NL);                                \
          if (in && hm < (HC) && (HC) > (HP)) mU |= 1u << (J);              \
          if (in && hm > (HC) && (HC) < (HP)) mL |= 1u << (J);              \
          hm = (HC); }
        #pragma unroll
        for (int q = 0; q < 4; q++) {
          float4 nxt = cur;
          float n0;
          if (q < 3) { nxt = *(const float4*)&hcur[physi(base + q * 4 + 4)]; n0 = nxt.x; }
          else       { n0 = (base + 16 < NL) ? hcur[physi(base + 16)] : 0.0f; }
          PKSTEP(q * 4 + 0, cur.x, cur.y)
          PKSTEP(q * 4 + 1, cur.y, cur.z)
          PKSTEP(q * 4 + 2, cur.z, cur.w)
          PKSTEP(q * 4 + 3, cur.w, n0)
          cur = nxt;
        }
        #undef PKSTEP
      }
      // mask-derived summaries (identical values to the old in-loop trackers)
      int lmU = mU ? (base + 31 - __clz(mU)) : -1;
      int lmL = mL ? (base + 31 - __clz(mL)) : -1;
      int fpU = mU ? (base + __ffs(mU) - 1) : NL;   // first own peak
      int fpL = mL ? (base + __ffs(mL) - 1) : NL;
      int cU = __popc(mU), cL = __popc(mL);
      unsigned long long bUm = __ballot(mU != 0);
      unsigned long long bLm = __ballot(mL != 0);
      // wave summaries: owning lane stores directly (no scans)
      {
        int s;
        s = bUm ? (63 - __clzll((long long)bUm)) : 0;
        if (lane == s) wLU[wv] = bUm ? lmU : -1;
        s = bLm ? (63 - __clzll((long long)bLm)) : 0;
        if (lane == s) wLL[wv] = bLm ? lmL : -1;
        s = bUm ? (__ffsll(bUm) - 1) : 0;
        if (lane == s) wNU[wv] = bUm ? fpU : NL;
        s = bLm ? (__ffsll(bLm) - 1) : 0;
        if (lane == s) wNL[wv] = bLm ? fpL : NL;
      }
      // block peak-count totals (reduce only; same pairwise order as before)
      unsigned ict = ((unsigned)cU << 16) | (unsigned)cL;
      #pragma unroll
      for (int o = 1; o < 64; o <<= 1) {
        unsigned cc = __shfl_down(ict, o, 64);
        if (lane + o < 64) ict += cc;
      }
      if (lane == 0) wCT[wv] = ict;
      __syncthreads();   // S1
      if (t == 0) {      // 16-entry serial combine -> exclusive wave carries
        int aLU = -1, aLL = -1; unsigned tt = 0;
        for (int w = 0; w < NW; w++) {
          eLU[w] = aLU; aLU = max(aLU, wLU[w]);
          eLL[w] = aLL; aLL = max(aLL, wLL[w]);
          tt += wCT[w];
        }
        int aNU = NL, aNL = NL;
        for (int w = NW - 1; w >= 0; w--) {
          eNU[w] = aNU; aNU = min(aNU, wNU[w]);
          eNL[w] = aNL; aNL = min(aNL, wNL[w]);
        }
        sTot = tt;
      }
      __syncthreads();   // S2
      const unsigned tot = sTot;
      const int totU = (int)(tot >> 16), totL = (int)(tot & 0xffffu);

      // per-thread carries via ballot bit-ops + one dynamic shuffle each
      unsigned long long belowU = bUm & ((1ull << lane) - 1ull);
      unsigned long long belowL = bLm & ((1ull << lane) - 1ull);
      unsigned long long aboveU = (lane == 63) ? 0ull : (bUm & (~0ull << (lane + 1)));
      unsigned long long aboveL = (lane == 63) ? 0ull : (bLm & (~0ull << (lane + 1)));
      int slU = belowU ? (63 - __clzll((long long)belowU)) : 0;
      int slL = belowL ? (63 - __clzll((long long)belowL)) : 0;
      int snU = aboveU ? (__ffsll(aboveU) - 1) : 0;
      int snL = aboveL ? (__ffsll(aboveL) - 1) : 0;
      int gU  = __shfl(lmU, slU, 64);
      int gL  = __shfl(lmL, slL, 64);
      int gNU = __shfl(fpU, snU, 64);
      int gNL = __shfl(fpL, snL, 64);
      const int clU = belowU ? gU  : eLU[wv];
      const int clL = belowL ? gL  : eLL[wv];
      const int cnU = aboveU ? gNU : eNU[wv];
      const int cnL = aboveL ? gNL : eNL[wv];

      // Mx/Mn prefix carries only needed for the <2-peaks fallback (rare);
      // tot is block-uniform so the branch (and its barriers) is uniform.
      // R22: rmx/rmn recomputed HERE (hcur untouched since pass A; same
      // rolling order e0..e15 from -FMAXV/+FMAXV -> identical values).
      float crx = -FMAXV, crn = FMAXV;
      if (totU < 2 || totL < 2) {
        float rmx = -FMAXV, rmn = FMAXV;
        #pragma unroll
        for (int q = 0; q < 4; q++) {
          float4 v = *(const float4*)&hcur[physi(base + q * 4)];
          rmx = fmaxf(rmx, v.x); rmn = fminf(rmn, v.x);
          rmx = fmaxf(rmx, v.y); rmn = fminf(rmn, v.y);
          rmx = fmaxf(rmx, v.z); rmn = fminf(rmn, v.z);
          rmx = fmaxf(rmx, v.w); rmn = fminf(rmn, v.w);
        }
        float iMx = rmx, iMn = rmn;
        #pragma unroll
        for (int o = 1; o < 64; o <<= 1) {
          float fa = __shfl_up(iMx, o, 64);
          float fb = __shfl_up(iMn, o, 64);
          if (lane >= o) { iMx = fmaxf(iMx, fa); iMn = fminf(iMn, fb); }
        }
        if (lane == 63) { wMx[wv] = iMx; wMn[wv] = iMn; }
        __syncthreads();
        if (t == 0) {
          float aMx = -FMAXV, aMn = FMAXV;
          for (int w = 0; w < NW; w++) {
            eMx[w] = aMx; aMx = fmaxf(aMx, wMx[w]);
            eMn[w] = aMn; aMn = fminf(aMn, wMn[w]);
          }
        }
        __syncthreads();
        float pMx = __shfl_up(iMx, 1, 64); if (lane == 0) pMx = -FMAXV;
        float pMn = __shfl_up(iMn, 1, 64); if (lane == 0) pMn = FMAXV;
        crx = fmaxf(eMx[wv], pMx);
        crn = fminf(eMn[wv], pMn);
      }

      // pass C: envelopes + mean (frozen f32 ladder), streaming b128 chunks;
      // h_next = hc - mn written inline to the other buffer (dbuf subtract).
      double pm2 = 0.0, ph2 = 0.0;
      {
        float rx = crx, rn = crn;
        int curLU = clU, curLL = clL;
        float vl = hcur[physi(clU < 0 ? 0 : clU)];   // carry-in gathers
        float wl = hcur[physi(clL < 0 ? 0 : clL)];
        int gB = -0x7fffffff, gD = -0x7fffffff;
        float vr = 0.0f, wr = 0.0f;
        #define ENVSTEP(J, HC, OD) { int i = base + (J); float hc = (HC);   \
          rx = fmaxf(rx, hc); rn = fminf(rn, hc);                           \
          if ((mU >> (J)) & 1u) { curLU = i; vl = hc; }                     \
          if ((mL >> (J)) & 1u) { curLL = i; wl = hc; }                     \
          int lU = curLU, lL = curLL;                                       \
          unsigned highm = 0xFFFFFFFFu << (J); unsigned a;                  \
          a = mU & highm; int nUv = a ? (base + __ffs(a) - 1) : cnU;        \
          a = mL & highm; int nLv = a ? (base + __ffs(a) - 1) : cnL;        \
          if (nUv != gB) { gB = nUv; vr = hcur[physi(nUv >= NL ? NL - 1 : nUv)]; } \
          if (nLv != gD) { gD = nLv; wr = hcur[physi(nLv >= NL ? NL - 1 : nLv)]; } \
          int den = nUv - lU;                                               \
          float fracU = (float)(i - lU) / (float)(den > 0 ? den : 1);       \
          float envU = (den > 0) ? __builtin_fmaf(fracU, vr - vl, vl) : vl; \
          if (lU < 0) envU = vr;                                            \
          if (nUv >= NL) envU = vl;                                         \
          if (totU < 2) envU = rx;                                          \
          int den2 = nLv - lL;                                              \
          float fracL = (float)(i - lL) / (float)(den2 > 0 ? den2 : 1);     \
          float envL = (den2 > 0) ? __builtin_fmaf(fracL, wr - wl, wl) : wl;\
          if (lL < 0) envL = wr;                                            \
          if (nLv >= NL) envL = wl;                                         \
          if (totL < 2) envL = rn;                                          \
          float mn = 0.5f * (envU + envL);                                  \
          (OD) = hc - mn;                                                   \
          pm2 += (double)mn * (double)mn; ph2 += (double)hc * (double)hc; }
        #pragma unroll
        for (int q = 0; q < 4; q++) {
          int i0 = base + q * 4;
          float4 hv4 = *(const float4*)&hcur[physi(i0)];
          float4 o4;
          ENVSTEP(q * 4 + 0, hv4.x, o4.x)
          ENVSTEP(q * 4 + 1, hv4.y, o4.y)
          ENVSTEP(q * 4 + 2, hv4.z, o4.z)
          ENVSTEP(q * 4 + 3, hv4.w, o4.w)
          *(float4*)&hnx[physi(i0)] = o4;
        }
        #undef ENVSTEP
      }
      // fused block reduction of (pm2, ph2): wave shuffle, publish, t0 combines
      #pragma unroll
      for (int o = 1; o < 64; o <<= 1) {
        double a = __shfl_down(pm2, o, 64);
        double b = __shfl_down(ph2, o, 64);
        if (lane + o < 64) { pm2 += a; ph2 += b; }
      }
      if (lane == 0) { tA[wv] = pm2; tB[wv] = ph2; }
      // ---- grid barrier + convergence decision ----
      ep++;
      __syncthreads();   // orders tA/tB (and hnx writes) before t0 / reuse
      if (t == 0) {
        double sA = 0.0, sB = 0.0;
        for (int w = 0; w < NW; w++) { sA += tA[w]; sB += tB[w]; }
        atomicAdd(&sdsl[(k * N_ITER + it) * 2 + 0], sA);
        atomicAdd(&sdsl[(k * N_ITER + it) * 2 + 1], sB);
        __hip_atomic_fetch_add(cnt, 1u, __ATOMIC_ACQ_REL, __HIP_MEMORY_SCOPE_AGENT);
        unsigned tgt = ep * gridDim.x;
        while (__hip_atomic_load(cnt, __ATOMIC_ACQUIRE, __HIP_MEMORY_SCOPE_AGENT) < tgt)
          __builtin_amdgcn_s_sleep(1);
        double m2 = __hip_atomic_load(&sdsl[(k * N_ITER + it) * 2 + 0],
                                      __ATOMIC_RELAXED, __HIP_MEMORY_SCOPE_AGENT);
        double h2 = __hip_atomic_load(&sdsl[(k * N_ITER + it) * 2 + 1],
                                      __ATOMIC_RELAXED, __HIP_MEMORY_SCOPE_AGENT);
        sFlag = (m2 / (h2 + 1e-8) < 0.05) ? 1 : 0;
      }
      __syncthreads();
      if (sFlag) break;   // converged: keep OLD buffer (h frozen, JAX latch)
      off ^= HSZ;         // accept h_next: uniform flip, no barrier needed
    }

    // ------------- flatness test + outputs (f32 values, f64 sums) -------------
    float* hcur = hbuf + off;
    double s1 = 0.0, s2 = 0.0, s3 = 0.0, s4 = 0.0;
    {
      float rb = 0.0f;   // res-h at base+NC (next thread's first element)
      if (base + NC < NL) rb = res[base + NC] - hcur[physi(base + NC)];
      float4 rv4 = *(const float4*)&res[base];
      float4 hv4 = *(const float4*)&hcur[physi(base)];
      float e0 = rv4.x - hv4.x, e1 = rv4.y - hv4.y,
            e2 = rv4.z - hv4.z, e3 = rv4.w - hv4.w;
      #define FLSTEP(J, CUR, NXT) { int i = base + (J);                     \
        s1 += (double)(CUR); s2 += (double)(CUR) * (double)(CUR);           \
        if (i + 1 < NL) { float dd = (NXT) - (CUR);                         \
          s3 += (double)dd; s4 += (double)dd * (double)dd; } }
      #pragma unroll
      for (int q = 0; q < 4; q++) {
        float c0 = e0, c1 = e1, c2 = e2, c3 = e3;
        float n0;
        if (q < 3) {
          int i0 = base + q * 4 + 4;
          rv4 = *(const float4*)&res[i0];
          hv4 = *(const float4*)&hcur[physi(i0)];
          e0 = rv4.x - hv4.x; e1 = rv4.y - hv4.y;
          e2 = rv4.z - hv4.z; e3 = rv4.w - hv4.w;
          n0 = e0;
        } else n0 = rb;
        FLSTEP(q * 4 + 0, c0, c1)
        FLSTEP(q * 4 + 1, c1, c2)
        FLSTEP(q * 4 + 2, c2, c3)
        FLSTEP(q * 4 + 3, c3, n0)
      }
      #undef FLSTEP
    }
    #pragma unroll
    for (int o = 1; o < 64; o <<= 1) {
      double a = __shfl_down(s1, o, 64);
      double b = __shfl_down(s2, o, 64);
      double c = __shfl_down(s3, o, 64);
      double d = __shfl_down(s4, o, 64);
      if (lane + o < 64) { s1 += a; s2 += b; s3 += c; s4 += d; }
    }
    if (lane == 0) { tA[wv] = s1; tB[wv] = s2; tC[wv] = s3; tD[wv] = s4; }
    __syncthreads();   // orders publishes AND all cross-thread h/res reads above
    if (t == 0) {
      double S1 = 0.0, S2 = 0.0, S3 = 0.0, S4 = 0.0;
      for (int w = 0; w < NW; w++) { S1 += tA[w]; S2 += tB[w]; S3 += tC[w]; S4 += tD[w]; }
      atomicAdd(&flsl[k * 4 + 0], S1);
      atomicAdd(&flsl[k * 4 + 1], S2);
      atomicAdd(&flsl[k * 4 + 2], S3);
      atomicAdd(&flsl[k * 4 + 3], S4);
    }
    // outputs: IMF k = h; res -= h; h <- new res (current buffer)
    #pragma unroll
    for (int q = 0; q < NC / 4; q++) {
      int i0 = base + q * 4;
      int p0 = physi(i0);
      float4 rv = *(const float4*)&res[i0];
      float4 hv = *(const float4*)&hcur[p0];
      float4 rq = make_float4(rv.x - hv.x, rv.y - hv.y, rv.z - hv.z, rv.w - hv.w);
      *(float4*)&outk[i0] = hv;
      *(float4*)&res[i0] = rq;
      *(float4*)&hcur[p0] = rq;
    }
    // ---- grid barrier + flatness decision ----
    ep++;
    __syncthreads();
    if (t == 0) {
      __hip_atomic_fetch_add(cnt, 1u, __ATOMIC_ACQ_REL, __HIP_MEMORY_SCOPE_AGENT);
      unsigned tgt = ep * gridDim.x;
      while (__hip_atomic_load(cnt, __ATOMIC_ACQUIRE, __HIP_MEMORY_SCOPE_AGENT) < tgt)
        __builtin_amdgcn_s_sleep(1);
      double S1 = __hip_atomic_load(&flsl[k * 4 + 0], __ATOMIC_RELAXED, __HIP_MEMORY_SCOPE_AGENT);
      double S2 = __hip_atomic_load(&flsl[k * 4 + 1], __ATOMIC_RELAXED, __HIP_MEMORY_SCOPE_AGENT);
      double S3 = __hip_atomic_load(&flsl[k * 4 + 2], __ATOMIC_RELAXED, __HIP_MEMORY_SCOPE_AGENT);
      double S4 = __hip_atomic_load(&flsl[k * 4 + 3], __ATOMIC_RELAXED, __HIP_MEMORY_SCOPE_AGENT);
      double nr = (double)NB * (double)NL;
      double nd = (double)NB * (double)(NL - 1);
      double varr = (S2 - S1 * S1 / nr) / (nr - 1.0);
      double vard = (S4 - S3 * S3 / nd) / (nd - 1.0);
      sFlag = (vard < 0.05 * varr) ? 1 : 0;
    }
    __syncthreads();
    done = done || (sFlag != 0);
  }
}

extern "C" void kernel_launch(void* const* d_in, const int* in_sizes, int n_in,
                              void* d_out, int out_size, void* d_ws, size_t ws_size,
                              hipStream_t stream) {
  const float* x = (const float*)d_in[0];
  float* out = (float*)d_out;
  // ws layout: [0] barrier counter; [256] sd slots (6*12*2 dbl); [1408] flat slots (6*4 dbl)
  size_t zb = ws_size < 4096 ? ws_size : 4096;
  hipMemsetAsync(d_ws, 0, zb, stream);
  unsigned* cnt = (unsigned*)d_ws;
  double* sdsl = (double*)((char*)d_ws + 256);
  double* flsl = (double*)((char*)d_ws + 256 + (size_t)N_IMFS * N_ITER * 2 * 8);
  hipLaunchKernelGGL(emd_main, dim3(NB), dim3(NT), 0, stream, x, out, cnt, sdsl, flsl);
}